// Round 5
// baseline (144.278 us; speedup 1.0000x reference)
//
#include <hip/hip_runtime.h>

// log1p thresholds (fp32): ln(6), ln(26), ln(51)
#define THR1 1.7917594909667969f
#define THR2 3.2580966949462891f
#define THR3 3.9318256378173828f
#define W1 0.2f
#define W2 30.0f
#define W3 2500.0f
#define W4 20000.0f

#define BLOCK 256
#define SPT 2                       // float4s per thread per array per stage
#define STAGE_F4 (BLOCK * SPT)      // 512 float4s = 8 KB per array per stage

typedef float f32x4 __attribute__((ext_vector_type(4)));

__device__ __forceinline__ float bucket_w(float y) {
    return (y < THR1) ? W1 : ((y < THR2) ? W2 : ((y < THR3) ? W3 : W4));
}

__device__ __forceinline__ void accum(f32x4 a, f32x4 b, float& num, float& den) {
    #pragma unroll
    for (int k = 0; k < 4; ++k) {
        const float t = b[k];
        const float w = bucket_w(t);
        num += w * fabsf(t - a[k]);
        den += w;
    }
}

// Issue one stage of DMA global->LDS for one array.
// HW writes lane l at lds_base + l*16, so lds base must be wave-uniform and
// the LDS layout linear in lane order (guide §5: wave-uniform base + lane*size).
__device__ __forceinline__ void stage_one(const f32x4* __restrict__ src,
                                          f32x4* lds_buf, int f4base, int tid) {
    const int wbase = tid & ~63;    // wave-uniform lane-0 element index
    #pragma unroll
    for (int s = 0; s < SPT; ++s) {
        const f32x4* g = src + f4base + s * BLOCK + tid;        // per-lane global addr
        f32x4* l = lds_buf + s * BLOCK + wbase;                 // wave-uniform LDS base
        __builtin_amdgcn_global_load_lds(
            (const __attribute__((address_space(1))) unsigned int*)g,
            (__attribute__((address_space(3))) unsigned int*)l,
            16, 0, 0);
    }
}

// Probe: does the global_load_lds DMA path bypass the ~3.3 TB/s per-CU
// read-miss cap that VGPR-returning loads hit? Double-buffered LDS staging,
// raw s_barrier + counted vmcnt (never 0 mid-loop) so the next stage's loads
// stay in flight across barriers.
__global__ __launch_bounds__(BLOCK) void mae_stage1(
    const float* __restrict__ y_pred,
    const float* __restrict__ y_true,
    float2* __restrict__ partials,   // one (num,den) per block
    int n)
{
    __shared__ f32x4 bufA[2][STAGE_F4];   // 16 KB
    __shared__ f32x4 bufB[2][STAGE_F4];   // 16 KB  -> 32 KB/block, 5 blocks/CU

    const int n4 = n >> 2;
    const int nstages = n4 / STAGE_F4;             // 7680 for this shape (exact)
    const f32x4* __restrict__ p4 = (const f32x4*)y_pred;
    const f32x4* __restrict__ t4 = (const f32x4*)y_true;
    const int tid = threadIdx.x;

    float num = 0.0f, den = 0.0f;

    int c = blockIdx.x;
    int cur = 0;
    if (c < nstages) {                              // prologue: prefetch first stage
        stage_one(p4, &bufA[0][0], c * STAGE_F4, tid);
        stage_one(t4, &bufB[0][0], c * STAGE_F4, tid);
    }

    for (; c < nstages; c += gridDim.x) {
        const int cn = c + (int)gridDim.x;
        const bool have_next = (cn < nstages);
        if (have_next) {                            // prefetch next into other buffer
            stage_one(p4, &bufA[cur ^ 1][0], cn * STAGE_F4, tid);
            stage_one(t4, &bufB[cur ^ 1][0], cn * STAGE_F4, tid);
            asm volatile("s_waitcnt vmcnt(4)" ::: "memory");  // current stage's 4 done; next 4 in flight
        } else {
            asm volatile("s_waitcnt vmcnt(0)" ::: "memory");  // epilogue drain
        }
        __builtin_amdgcn_sched_barrier(0);
        __builtin_amdgcn_s_barrier();               // all waves' DMA for buf[cur] landed

        #pragma unroll
        for (int s = 0; s < SPT; ++s) {
            const f32x4 a = bufA[cur][s * BLOCK + tid];
            const f32x4 b = bufB[cur][s * BLOCK + tid];
            accum(a, b, num, den);
        }

        asm volatile("s_waitcnt lgkmcnt(0)" ::: "memory");    // my ds_reads retired
        __builtin_amdgcn_sched_barrier(0);
        __builtin_amdgcn_s_barrier();               // buf[cur] free for overwrite
        cur ^= 1;
    }

    // tail: elements beyond the full stages (zero for this problem shape)
    for (int j = nstages * STAGE_F4 * 4 + blockIdx.x * BLOCK + threadIdx.x; j < n;
         j += gridDim.x * BLOCK) {
        const float aa = y_pred[j];
        const float bb = y_true[j];
        const float w = bucket_w(bb);
        num += w * fabsf(bb - aa);
        den += w;
    }

    // 64-lane wave reduction
    #pragma unroll
    for (int off = 32; off > 0; off >>= 1) {
        num += __shfl_down(num, off, 64);
        den += __shfl_down(den, off, 64);
    }

    __shared__ float s_num[4];
    __shared__ float s_den[4];
    const int wave = threadIdx.x >> 6;
    const int lane = threadIdx.x & 63;
    if (lane == 0) { s_num[wave] = num; s_den[wave] = den; }
    __syncthreads();

    if (threadIdx.x == 0) {
        partials[blockIdx.x] = make_float2(s_num[0] + s_num[1] + s_num[2] + s_num[3],
                                           s_den[0] + s_den[1] + s_den[2] + s_den[3]);
    }
}

__global__ __launch_bounds__(BLOCK) void mae_stage2(
    const float2* __restrict__ partials, int nblocks, float* __restrict__ out)
{
    float num = 0.0f, den = 0.0f;
    for (int i = threadIdx.x; i < nblocks; i += BLOCK) {
        const float2 v = partials[i];
        num += v.x; den += v.y;
    }

    #pragma unroll
    for (int off = 32; off > 0; off >>= 1) {
        num += __shfl_down(num, off, 64);
        den += __shfl_down(den, off, 64);
    }

    __shared__ float s_num[4];
    __shared__ float s_den[4];
    const int wave = threadIdx.x >> 6;
    const int lane = threadIdx.x & 63;
    if (lane == 0) { s_num[wave] = num; s_den[wave] = den; }
    __syncthreads();

    if (threadIdx.x == 0) {
        const float bn = s_num[0] + s_num[1] + s_num[2] + s_num[3];
        const float bd = s_den[0] + s_den[1] + s_den[2] + s_den[3];
        out[0] = bn / bd;
    }
}

extern "C" void kernel_launch(void* const* d_in, const int* in_sizes, int n_in,
                              void* d_out, int out_size, void* d_ws, size_t ws_size,
                              hipStream_t stream)
{
    const float* y_pred = (const float*)d_in[0];
    const float* y_true = (const float*)d_in[1];
    float* out = (float*)d_out;
    float2* partials = (float2*)d_ws;       // grid float2s, fully overwritten each call
    const int n = in_sizes[0];

    const int n4 = n >> 2;
    const int nstages = n4 / STAGE_F4;

    int grid = 1920;                         // 7680 stages / 1920 = 4 per block (exact)
    if (nstages < grid) grid = (nstages > 0) ? nstages : 1;

    mae_stage1<<<grid, BLOCK, 0, stream>>>(y_pred, y_true, partials, n);
    mae_stage2<<<1, BLOCK, 0, stream>>>(partials, grid, out);
}

// Round 6
// 135.998 us; speedup vs baseline: 1.0609x; 1.0609x over previous
//
#include <hip/hip_runtime.h>

// log1p thresholds (fp32): ln(6), ln(26), ln(51)
#define THR1 1.7917594909667969f
#define THR2 3.2580966949462891f
#define THR3 3.9318256378173828f
#define W1 0.2f
#define W2 30.0f
#define W3 2500.0f
#define W4 20000.0f

#define BLOCK 256
#define P 4                         // float4s per thread, single pass (8 loads in one burst)

typedef float f32x4 __attribute__((ext_vector_type(4)));

__device__ __forceinline__ f32x4 ntload(const f32x4* __restrict__ p) {
    // non-temporal: no L1 allocate (streaming data, zero reuse).
    // Best measured variant: ~37us stage1 = ~3.4 TB/s effective read.
    // NOTE (session findings): this is the per-CU read-miss-tracking ceiling
    // (~64 x 128B lines in flight/CU, Little's law -> 3.35 TB/s chip-wide).
    // VGPR loads, nt loads, and global_load_lds DMA all pin at it (r0-r5).
    // Do NOT fuse stage2 via per-block __threadfence + device atomic:
    // 3840 serialized device-scope fences cost ~210us (r3).
    return __builtin_nontemporal_load(p);
}

__device__ __forceinline__ float bucket_w(float y) {
    return (y < THR1) ? W1 : ((y < THR2) ? W2 : ((y < THR3) ? W3 : W4));
}

__device__ __forceinline__ void accum(f32x4 a, f32x4 b, float& num, float& den) {
    #pragma unroll
    for (int k = 0; k < 4; ++k) {
        const float t = b[k];
        const float w = bucket_w(t);
        num += w * fabsf(t - a[k]);
        den += w;
    }
}

// Single-pass: each block owns exactly one CHUNK (= BLOCK*P float4s) of both
// arrays; each thread issues its entire 8x16B non-temporal load burst once.
__global__ __launch_bounds__(BLOCK) void mae_stage1(
    const float* __restrict__ y_pred,
    const float* __restrict__ y_true,
    float2* __restrict__ partials,   // one (num,den) per block
    int n)
{
    const int n4 = n >> 2;
    const int CHUNK = BLOCK * P;               // 1024 float4s per block
    const int nfull = n4 / CHUNK;              // fully-covered chunks (exact here)
    const f32x4* __restrict__ p4 = (const f32x4*)y_pred;
    const f32x4* __restrict__ t4 = (const f32x4*)y_true;

    float num = 0.0f, den = 0.0f;

    if (blockIdx.x < nfull) {
        const int base = blockIdx.x * CHUNK + threadIdx.x;
        const f32x4 a0 = ntload(p4 + base + 0 * BLOCK);
        const f32x4 b0 = ntload(t4 + base + 0 * BLOCK);
        const f32x4 a1 = ntload(p4 + base + 1 * BLOCK);
        const f32x4 b1 = ntload(t4 + base + 1 * BLOCK);
        const f32x4 a2 = ntload(p4 + base + 2 * BLOCK);
        const f32x4 b2 = ntload(t4 + base + 2 * BLOCK);
        const f32x4 a3 = ntload(p4 + base + 3 * BLOCK);
        const f32x4 b3 = ntload(t4 + base + 3 * BLOCK);
        accum(a0, b0, num, den);
        accum(a1, b1, num, den);
        accum(a2, b2, num, den);
        accum(a3, b3, num, den);
    }

    // tail: elements beyond the full chunks (zero for this problem shape)
    for (int j = nfull * CHUNK * 4 + blockIdx.x * BLOCK + threadIdx.x; j < n;
         j += gridDim.x * BLOCK) {
        const float aa = y_pred[j];
        const float bb = y_true[j];
        const float w = bucket_w(bb);
        num += w * fabsf(bb - aa);
        den += w;
    }

    // 64-lane wave reduction
    #pragma unroll
    for (int off = 32; off > 0; off >>= 1) {
        num += __shfl_down(num, off, 64);
        den += __shfl_down(den, off, 64);
    }

    __shared__ float s_num[4];
    __shared__ float s_den[4];
    const int wave = threadIdx.x >> 6;
    const int lane = threadIdx.x & 63;
    if (lane == 0) { s_num[wave] = num; s_den[wave] = den; }
    __syncthreads();

    if (threadIdx.x == 0) {
        partials[blockIdx.x] = make_float2(s_num[0] + s_num[1] + s_num[2] + s_num[3],
                                           s_den[0] + s_den[1] + s_den[2] + s_den[3]);
    }
}

__global__ __launch_bounds__(BLOCK) void mae_stage2(
    const float2* __restrict__ partials, int nblocks, float* __restrict__ out)
{
    float num = 0.0f, den = 0.0f;
    for (int i = threadIdx.x; i < nblocks; i += BLOCK) {
        const float2 v = partials[i];
        num += v.x; den += v.y;
    }

    #pragma unroll
    for (int off = 32; off > 0; off >>= 1) {
        num += __shfl_down(num, off, 64);
        den += __shfl_down(den, off, 64);
    }

    __shared__ float s_num[4];
    __shared__ float s_den[4];
    const int wave = threadIdx.x >> 6;
    const int lane = threadIdx.x & 63;
    if (lane == 0) { s_num[wave] = num; s_den[wave] = den; }
    __syncthreads();

    if (threadIdx.x == 0) {
        const float bn = s_num[0] + s_num[1] + s_num[2] + s_num[3];
        const float bd = s_den[0] + s_den[1] + s_den[2] + s_den[3];
        out[0] = bn / bd;
    }
}

extern "C" void kernel_launch(void* const* d_in, const int* in_sizes, int n_in,
                              void* d_out, int out_size, void* d_ws, size_t ws_size,
                              hipStream_t stream)
{
    const float* y_pred = (const float*)d_in[0];
    const float* y_true = (const float*)d_in[1];
    float* out = (float*)d_out;
    float2* partials = (float2*)d_ws;       // grid float2s, fully overwritten each call
    const int n = in_sizes[0];

    const int n4 = n >> 2;
    const int CHUNK = BLOCK * P;
    int grid = n4 / CHUNK;                   // 3840 for this shape (exact)
    if (grid * CHUNK * 4 < n) grid += 1;     // one extra block for any tail
    if (grid < 1) grid = 1;

    mae_stage1<<<grid, BLOCK, 0, stream>>>(y_pred, y_true, partials, n);
    mae_stage2<<<1, BLOCK, 0, stream>>>(partials, grid, out);
}